// Round 14
// baseline (1422.266 us; speedup 1.0000x reference)
//
#include <hip/hip_runtime.h>

typedef __bf16 bf16_t;
typedef __bf16 bf16x8 __attribute__((ext_vector_type(8)));
typedef __bf16 bf16x4 __attribute__((ext_vector_type(4)));
typedef __bf16 bf16x2 __attribute__((ext_vector_type(2)));
typedef float f32x4 __attribute__((ext_vector_type(4)));

#define SCALE 0.17677669529663687f

__device__ __forceinline__ f32x4 mfma16(bf16x8 a, bf16x8 b, f32x4 c) {
  return __builtin_amdgcn_mfma_f32_16x16x32_bf16(a, b, c, 0, 0, 0);
}

// XOR-swizzled LDS byte offset: 16B-granule index XORed with (row&7).
__device__ __forceinline__ int swz(int row, int colByte, int strideB) {
  return row * strideB + ((((colByte >> 4) ^ (row & 7)) << 4) | (colByte & 15));
}

// lgkm-only barrier: orders LDS producer->consumer, leaves global loads in
// flight. Proven r5-r13.
__device__ __forceinline__ void barrier_nd() {
  asm volatile("s_waitcnt lgkmcnt(0)" ::: "memory");
  __builtin_amdgcn_s_barrier();
  asm volatile("" ::: "memory");
}

union CvtU { bf16x2 h; unsigned int u; };
union PaU { unsigned int u[4]; bf16x8 v; };

// ws: bf16 weights. q_wb [0,36864) PRE-SCALED by SCALE, kv_wb [36864,110592),
// proj_wb [110592,147456). 294912 bytes.
__global__ void prep(const float* __restrict__ qw, const float* __restrict__ kvw,
                     const float* __restrict__ pw, bf16_t* __restrict__ wsb) {
  int i = blockIdx.x * 256 + threadIdx.x;
#pragma unroll
  for (int j = 0; j < 4; ++j) {
    int e = i * 4 + j;
    float v;
    if (e < 36864) v = qw[e] * SCALE;
    else if (e < 110592) v = kvw[e - 36864];
    else v = pw[e - 110592];
    wsb[e] = (bf16_t)v;
  }
}

template <bool WS>
__device__ __forceinline__ bf16x8 ldw(const bf16_t* __restrict__ wb,
                                      const float* __restrict__ wf, int off) {
  if constexpr (WS) {
    return *(const bf16x8*)(wb + off);
  } else {
    const float4* p = (const float4*)(wf + off);
    float4 a = p[0], c = p[1];
    bf16x8 r;
    r[0] = (bf16_t)a.x; r[1] = (bf16_t)a.y; r[2] = (bf16_t)a.z; r[3] = (bf16_t)a.w;
    r[4] = (bf16_t)c.x; r[5] = (bf16_t)c.y; r[6] = (bf16_t)c.z; r[7] = (bf16_t)c.w;
    return r;
  }
}

// Persistent: 256 blocks (1/CU) x 32 windows. 512 threads = 8 waves:
// waves 0-5 compute, waves 6-7 loaders (double-buffer x1,x2 one window ahead;
// prefetch state lives in LDS -> nothing spills, nothing crosses barriers in
// VGPRs). LDS 144 KB:
//   XIN[2]  @ 0 / 24576      : x2 bf16 [64][384B] swz -> Q -> att-out
//   X1IN[2] @ 49152 / 73728  : x1 bf16 [64][384B] swz
//   RK      @ 98304          : K [64][384B] swz
//   RV      @ 122880         : V^T [192][128B] swz
// Per window only TWO barriers: {post-A} and {post-attn}. Phase-B wave ==
// attention wave for its Q tile (rows rb*32, channels cg3*64 = 2 heads), so
// no B->attn barrier. Loaders work between the two barriers.
template <bool WS>
__global__ __launch_bounds__(512, 2) void wca_main(
    const float* __restrict__ x1, const float* __restrict__ x2,
    const float* __restrict__ mask,
    const float* __restrict__ qw_f, const float* __restrict__ qb,
    const float* __restrict__ kvw_f, const float* __restrict__ kvb,
    const float* __restrict__ pw_f, const float* __restrict__ pb,
    const float* __restrict__ table,
    const bf16_t* __restrict__ wsb,
    float* __restrict__ out) {
  extern __shared__ char smem[];
  char* RK = smem + 98304;
  char* RV = smem + 122880;

  const int t = threadIdx.x;
  const int w = t >> 6, l = t & 63, lo = l & 15, hi = l >> 4;
  const int bid = blockIdx.x;

  const bf16_t* q_wb = wsb;
  const bf16_t* kv_wb = wsb + 36864;
  const bf16_t* p_wb = wsb + 110592;

  // compute-wave role (waves 0..5): rb = row half, cg3 = channel third
  const int rb = (w >= 3 && w < 6) ? 1 : 0;
  const int cg3 = w - rb * 3;  // 0..2 for compute waves

  // ---------- prologue: loaders stage window bid*32 into buffer 0 ----------
  if (w >= 6) {
    const int L = (w - 6) * 64 + l;  // 0..127
    const float4* s2 = (const float4*)(x2 + (size_t)(bid * 32) * 12288);
    const float4* s1 = (const float4*)(x1 + (size_t)(bid * 32) * 12288);
#pragma unroll
    for (int ch = 0; ch < 12; ++ch) {
      int G = ch * 128 + L;            // 16B-granule id [0,1536)
      int n = G / 24, g = G - n * 24;
      float4 a = s2[2 * G], b = s2[2 * G + 1];
      bf16x8 v;
      v[0] = (bf16_t)a.x; v[1] = (bf16_t)a.y; v[2] = (bf16_t)a.z; v[3] = (bf16_t)a.w;
      v[4] = (bf16_t)b.x; v[5] = (bf16_t)b.y; v[6] = (bf16_t)b.z; v[7] = (bf16_t)b.w;
      *(bf16x8*)(smem + swz(n, g * 16, 384)) = v;
      a = s1[2 * G]; b = s1[2 * G + 1];
      v[0] = (bf16_t)a.x; v[1] = (bf16_t)a.y; v[2] = (bf16_t)a.z; v[3] = (bf16_t)a.w;
      v[4] = (bf16_t)b.x; v[5] = (bf16_t)b.y; v[6] = (bf16_t)b.z; v[7] = (bf16_t)b.w;
      *(bf16x8*)(smem + 49152 + swz(n, g * 16, 384)) = v;
    }
  }
  barrier_nd();

#pragma unroll 1
  for (int j = 0; j < 32; ++j) {
    const int win = bid * 32 + j;
    const int cur = j & 1;
    char* xin = smem + cur * 24576;            // x2 -> Q -> att-out
    const char* x1s = smem + 49152 + cur * 24576;

    // ---------- phase A: KV proj (compute waves) ----------
    if (w < 6) {
      const int part = (w >= 3) ? 1 : 0;       // 0 = K, 1 = V
      const int kcol = cg3 * 64;
      bf16x8 wA[6][4];
#pragma unroll
      for (int kk = 0; kk < 6; ++kk)
#pragma unroll
        for (int ct = 0; ct < 4; ++ct) {
          int row = part * 192 + kcol + ct * 16 + lo;
          wA[kk][ct] = ldw<WS>(kv_wb, kvw_f, row * 192 + kk * 32 + hi * 8);
        }
      f32x4 acc[4][4];
#pragma unroll
      for (int rt = 0; rt < 4; ++rt)
#pragma unroll
        for (int ct = 0; ct < 4; ++ct) { f32x4 z = {0.f, 0.f, 0.f, 0.f}; acc[rt][ct] = z; }
#pragma unroll
      for (int kk = 0; kk < 6; ++kk) {
        bf16x8 a[4];
#pragma unroll
        for (int rt = 0; rt < 4; ++rt)
          a[rt] = *(const bf16x8*)(xin + swz(rt * 16 + lo, (kk * 4 + hi) * 16, 384));
#pragma unroll
        for (int rt = 0; rt < 4; ++rt)
#pragma unroll
          for (int ct = 0; ct < 4; ++ct)
            acc[rt][ct] = mfma16(a[rt], wA[kk][ct], acc[rt][ct]);
      }
      if (part == 0) {
#pragma unroll
        for (int ct = 0; ct < 4; ++ct) {
          int och = kcol + ct * 16 + lo;
          float bv = kvb[och];
#pragma unroll
          for (int rt = 0; rt < 4; ++rt)
#pragma unroll
            for (int i = 0; i < 4; ++i)
              *(bf16_t*)(RK + swz(rt * 16 + hi * 4 + i, och * 2, 384)) =
                  (bf16_t)(acc[rt][ct][i] + bv);
        }
      } else {
#pragma unroll
        for (int ct = 0; ct < 4; ++ct) {
          int och = kcol + ct * 16 + lo;
          float bv = kvb[192 + och];
#pragma unroll
          for (int rt = 0; rt < 4; ++rt) {
            int n0 = rt * 16 + hi * 4;
            bf16x4 pk;
#pragma unroll
            for (int i = 0; i < 4; ++i) pk[i] = (bf16_t)(acc[rt][ct][i] + bv);
            *(bf16x4*)(RV + swz(och, n0 * 2, 128)) = pk;
          }
        }
      }
    }
    barrier_nd();  // #1: RK/RV ready; x2(XIN[cur]) dead; out(j-1) reads drained

    // ---------- phase B + attention (compute) | next-window loads (loaders) ----------
    if (w < 6) {
      // ----- phase B: Q proj from X1IN -> Q into XIN[cur] -----
      {
        bf16x8 wB[6][4];
#pragma unroll
        for (int kk = 0; kk < 6; ++kk)
#pragma unroll
          for (int ct = 0; ct < 4; ++ct) {
            int col = cg3 * 64 + ct * 16 + lo;
            wB[kk][ct] = ldw<WS>(q_wb, qw_f, col * 192 + kk * 32 + hi * 8);
          }
        f32x4 acc[2][4];
#pragma unroll
        for (int rt = 0; rt < 2; ++rt)
#pragma unroll
          for (int ct = 0; ct < 4; ++ct) { f32x4 z = {0.f, 0.f, 0.f, 0.f}; acc[rt][ct] = z; }
#pragma unroll
        for (int kk = 0; kk < 6; ++kk) {
          bf16x8 a[2];
#pragma unroll
          for (int rt = 0; rt < 2; ++rt)
            a[rt] = *(const bf16x8*)(x1s + swz(rb * 32 + rt * 16 + lo, (kk * 4 + hi) * 16, 384));
#pragma unroll
          for (int rt = 0; rt < 2; ++rt)
#pragma unroll
            for (int ct = 0; ct < 4; ++ct)
              acc[rt][ct] = mfma16(a[rt], wB[kk][ct], acc[rt][ct]);
        }
#pragma unroll
        for (int ct = 0; ct < 4; ++ct) {
          int col = cg3 * 64 + ct * 16 + lo;
          float qv = qb[col];
#pragma unroll
          for (int rt = 0; rt < 2; ++rt)
#pragma unroll
            for (int i = 0; i < 4; ++i) {
              int row = rb * 32 + rt * 16 + hi * 4 + i;
              float val = WS ? (acc[rt][ct][i] + qv * SCALE)
                             : (acc[rt][ct][i] + qv) * SCALE;
              *(bf16_t*)(xin + swz(row, col * 2, 384)) = (bf16_t)val;
            }
        }
      }
      // ----- attention: rows rb*32..+32, heads cg3*2 + hq (same wave as B) -----
      {
        const float* maskb = mask + (size_t)(win & 1023) * 4096;
        f32x4 mk[2][4];
        int ridx[2][4][4];
#pragma unroll
        for (int rts = 0; rts < 2; ++rts) {
          int r = rb * 32 + rts * 16 + lo;
#pragma unroll
          for (int ct = 0; ct < 4; ++ct) {
            mk[rts][ct] = *(const f32x4*)(maskb + r * 64 + ct * 16 + hi * 4);
#pragma unroll
            for (int i = 0; i < 4; ++i) {
              int cc = ct * 16 + hi * 4 + i;
              ridx[rts][ct][i] = (((r >> 3) - (cc >> 3) + 7) * 15 + ((r & 7) - (cc & 7) + 7)) * 6;
            }
          }
        }
#pragma unroll
        for (int hq = 0; hq < 2; ++hq) {
          const int h = cg3 * 2 + hq;
#pragma unroll
          for (int rts = 0; rts < 2; ++rts) {
            const int rbase = rb * 32 + rts * 16;
            const int r = rbase + lo;
            bf16x8 qa = *(const bf16x8*)(xin + swz(r, h * 64 + hi * 16, 384));
            f32x4 s[4];
#pragma unroll
            for (int ct = 0; ct < 4; ++ct) {
              f32x4 ci;
#pragma unroll
              for (int i = 0; i < 4; ++i) ci[i] = table[ridx[rts][ct][i] + h];
              ci += mk[rts][ct];
              bf16x8 ka = *(const bf16x8*)(RK + swz(ct * 16 + lo, h * 64 + hi * 16, 384));
              s[ct] = mfma16(ka, qa, ci);  // lane holds S[r][ct*16+hi*4+i]
            }
            float mx = -1e30f;
#pragma unroll
            for (int ct = 0; ct < 4; ++ct)
#pragma unroll
              for (int i = 0; i < 4; ++i) mx = fmaxf(mx, s[ct][i]);
            mx = fmaxf(mx, __shfl_xor(mx, 16));
            mx = fmaxf(mx, __shfl_xor(mx, 32));
            float sum = 0.f;
#pragma unroll
            for (int ct = 0; ct < 4; ++ct)
#pragma unroll
              for (int i = 0; i < 4; ++i) {
                float p = __expf(s[ct][i] - mx);
                s[ct][i] = p;
                sum += p;
              }
            sum += __shfl_xor(sum, 16);
            sum += __shfl_xor(sum, 32);
            float rinv = 1.0f / sum;
            unsigned int word[4][2];
#pragma unroll
            for (int ct = 0; ct < 4; ++ct)
#pragma unroll
              for (int i2 = 0; i2 < 2; ++i2) {
                CvtU cu;
                cu.h[0] = (bf16_t)(s[ct][2 * i2] * rinv);
                cu.h[1] = (bf16_t)(s[ct][2 * i2 + 1] * rinv);
                word[ct][i2] = cu.u;
              }
            f32x4 o0 = {0.f, 0.f, 0.f, 0.f}, o1 = {0.f, 0.f, 0.f, 0.f};
#pragma unroll
            for (int k2 = 0; k2 < 2; ++k2) {
              PaU pa;
#pragma unroll
              for (int j2 = 0; j2 < 4; ++j2) {
                int src = lo + ((hi & 1) << 5) + ((j2 >> 1) << 4);
                unsigned int wa = (unsigned int)__shfl((int)word[2 * k2][j2 & 1], src);
                unsigned int wb = (unsigned int)__shfl((int)word[2 * k2 + 1][j2 & 1], src);
                pa.u[j2] = (hi & 2) ? wb : wa;
              }
              bf16x8 v0 = *(const bf16x8*)(RV + swz(h * 32 + lo, k2 * 64 + hi * 16, 128));
              bf16x8 v1 = *(const bf16x8*)(RV + swz(h * 32 + 16 + lo, k2 * 64 + hi * 16, 128));
              o0 = mfma16(pa.v, v0, o0);
              o1 = mfma16(pa.v, v1, o1);
            }
#pragma unroll
            for (int i = 0; i < 4; ++i) {
              int rr = rbase + hi * 4 + i;
              *(bf16_t*)(xin + swz(rr, h * 64 + lo * 2, 384)) = (bf16_t)o0[i];
              *(bf16_t*)(xin + swz(rr, h * 64 + 32 + lo * 2, 384)) = (bf16_t)o1[i];
            }
          }
        }
      }
    } else if (j < 31) {
      // ----- loaders: stage x1,x2 of window win+1 into buffers cur^1 -----
      const int L = (w - 6) * 64 + l;
      char* xd = smem + (cur ^ 1) * 24576;
      char* x1d = smem + 49152 + (cur ^ 1) * 24576;
      const float4* s2 = (const float4*)(x2 + (size_t)(win + 1) * 12288);
      const float4* s1 = (const float4*)(x1 + (size_t)(win + 1) * 12288);
#pragma unroll
      for (int ch = 0; ch < 12; ++ch) {
        int G = ch * 128 + L;
        int n = G / 24, g = G - n * 24;
        float4 a = s2[2 * G], b = s2[2 * G + 1];
        bf16x8 v;
        v[0] = (bf16_t)a.x; v[1] = (bf16_t)a.y; v[2] = (bf16_t)a.z; v[3] = (bf16_t)a.w;
        v[4] = (bf16_t)b.x; v[5] = (bf16_t)b.y; v[6] = (bf16_t)b.z; v[7] = (bf16_t)b.w;
        *(bf16x8*)(xd + swz(n, g * 16, 384)) = v;
        a = s1[2 * G]; b = s1[2 * G + 1];
        v[0] = (bf16_t)a.x; v[1] = (bf16_t)a.y; v[2] = (bf16_t)a.z; v[3] = (bf16_t)a.w;
        v[4] = (bf16_t)b.x; v[5] = (bf16_t)b.y; v[6] = (bf16_t)b.z; v[7] = (bf16_t)b.w;
        *(bf16x8*)(x1d + swz(n, g * 16, 384)) = v;
      }
    }
    barrier_nd();  // #2: att-out ready; loader writes drained

    // ---------- out proj: rows rb*32..+32, cols cg3*64..+64 ----------
    if (w < 6) {
      bf16x8 wO[6][4];
#pragma unroll
      for (int kk = 0; kk < 6; ++kk)
#pragma unroll
        for (int ct = 0; ct < 4; ++ct) {
          int col = cg3 * 64 + ct * 16 + lo;
          wO[kk][ct] = ldw<WS>(p_wb, pw_f, col * 192 + kk * 32 + hi * 8);
        }
      f32x4 acc[2][4];
#pragma unroll
      for (int rt = 0; rt < 2; ++rt)
#pragma unroll
        for (int ct = 0; ct < 4; ++ct) { f32x4 z = {0.f, 0.f, 0.f, 0.f}; acc[rt][ct] = z; }
#pragma unroll
      for (int kk = 0; kk < 6; ++kk) {
        bf16x8 a[2];
#pragma unroll
        for (int rt = 0; rt < 2; ++rt)
          a[rt] = *(const bf16x8*)(xin + swz(rb * 32 + rt * 16 + lo, (kk * 4 + hi) * 16, 384));
#pragma unroll
        for (int rt = 0; rt < 2; ++rt)
#pragma unroll
          for (int ct = 0; ct < 4; ++ct)
            acc[rt][ct] = mfma16(a[rt], wO[kk][ct], acc[rt][ct]);
      }
      float* outp = out + (size_t)win * 12288;
#pragma unroll
      for (int ct = 0; ct < 4; ++ct) {
        int col = cg3 * 64 + ct * 16 + lo;
        float bv = pb[col];
#pragma unroll
        for (int rt = 0; rt < 2; ++rt)
#pragma unroll
          for (int i = 0; i < 4; ++i)
            outp[(rb * 32 + rt * 16 + hi * 4 + i) * 192 + col] = acc[rt][ct][i] + bv;
      }
    }
    // no barrier here: out-proj reads of XIN[cur] drain at next iter's
    // barrier #1, before loaders overwrite XIN[cur] (they write only after
    // that barrier); phase A(j+1) touches only XIN[cur^1]/RK/RV, whose
    // readers all finished before barrier #2 above.
  }
}

extern "C" void kernel_launch(void* const* d_in, const int* in_sizes, int n_in,
                              void* d_out, int out_size, void* d_ws, size_t ws_size,
                              hipStream_t stream) {
  const float* x1 = (const float*)d_in[0];
  const float* x2 = (const float*)d_in[1];
  const float* mask = (const float*)d_in[2];
  const float* qw = (const float*)d_in[3];
  const float* qb = (const float*)d_in[4];
  const float* kvw = (const float*)d_in[5];
  const float* kvb = (const float*)d_in[6];
  const float* pw = (const float*)d_in[7];
  const float* pb = (const float*)d_in[8];
  const float* table = (const float*)d_in[9];
  float* out = (float*)d_out;
  bf16_t* wsb = (bf16_t*)d_ws;
  const int LDS_BYTES = 147456;
  if (ws_size >= 294912) {
    prep<<<144, 256, 0, stream>>>(qw, kvw, pw, wsb);
    wca_main<true><<<256, 512, LDS_BYTES, stream>>>(x1, x2, mask, qw, qb, kvw, kvb,
                                                    pw, pb, table, wsb, out);
  } else {
    wca_main<false><<<256, 512, LDS_BYTES, stream>>>(x1, x2, mask, qw, qb, kvw, kvb,
                                                     pw, pb, table, wsb, out);
  }
}

// Round 15
// 641.671 us; speedup vs baseline: 2.2165x; 2.2165x over previous
//
#include <hip/hip_runtime.h>

typedef __bf16 bf16_t;
typedef __bf16 bf16x8 __attribute__((ext_vector_type(8)));
typedef __bf16 bf16x4 __attribute__((ext_vector_type(4)));
typedef __bf16 bf16x2 __attribute__((ext_vector_type(2)));
typedef float f32x4 __attribute__((ext_vector_type(4)));

#define SCALE 0.17677669529663687f

__device__ __forceinline__ f32x4 mfma16(bf16x8 a, bf16x8 b, f32x4 c) {
  return __builtin_amdgcn_mfma_f32_16x16x32_bf16(a, b, c, 0, 0, 0);
}

// XOR-swizzled LDS byte offset: 16B-granule index XORed with (row&7).
__device__ __forceinline__ int swz(int row, int colByte, int strideB) {
  return row * strideB + ((((colByte >> 4) ^ (row & 7)) << 4) | (colByte & 15));
}

// lgkm-only barrier: orders LDS producer->consumer, leaves global loads in
// flight. Proven r5-r14.
__device__ __forceinline__ void barrier_nd() {
  asm volatile("s_waitcnt lgkmcnt(0)" ::: "memory");
  __builtin_amdgcn_s_barrier();
  asm volatile("" ::: "memory");
}

union CvtU { bf16x2 h; unsigned int u; };
union PaU { unsigned int u[4]; bf16x8 v; };

// ws: bf16 weights only. q_wb [0,36864) PRE-SCALED by SCALE, kv_wb
// [36864,110592), proj_wb [110592,147456). 294912 bytes.
__global__ void prep(const float* __restrict__ qw, const float* __restrict__ kvw,
                     const float* __restrict__ pw, bf16_t* __restrict__ wsb) {
  int i = blockIdx.x * 256 + threadIdx.x;
#pragma unroll
  for (int j = 0; j < 4; ++j) {
    int e = i * 4 + j;
    float v;
    if (e < 36864) v = qw[e] * SCALE;
    else if (e < 110592) v = kvw[e - 36864];
    else v = pw[e - 110592];
    wsb[e] = (bf16_t)v;
  }
}

template <bool WS>
__device__ __forceinline__ bf16x8 ldw(const bf16_t* __restrict__ wb,
                                      const float* __restrict__ wf, int off) {
  if constexpr (WS) {
    return *(const bf16x8*)(wb + off);
  } else {
    const float4* p = (const float4*)(wf + off);
    float4 a = p[0], c = p[1];
    bf16x8 r;
    r[0] = (bf16_t)a.x; r[1] = (bf16_t)a.y; r[2] = (bf16_t)a.z; r[3] = (bf16_t)a.w;
    r[4] = (bf16_t)c.x; r[5] = (bf16_t)c.y; r[6] = (bf16_t)c.z; r[7] = (bf16_t)c.w;
    return r;
  }
}

// One block = TWO windows (win0=2b, win1=2b+1). 512 threads = 8 waves.
// LDS = 144 KB -> 1 block/CU:
//   RA @      0 : [128][384B] x2 staged -> Q -> att-out (rows wv*64+n)
//   RK @  49152 : [128][384B] K (both windows)
//   RV @  98304 : [2][192][128B] V^T per window
// r15 = r7 + ONE change: the B->attn barrier is REMOVED. Proof: phase-B wave
// (wv=w>>2, rt2=(w>>1)&1, cg=w&1) writes Q rows [rt2*32,+32) x cols
// [cg*96,+96); the attention wave uses the identical (wv, rt32, hh) decode
// and reads exactly that tile (3 heads x 32ch = 96 cols at hh*96). K/V are
// synced at the A-barrier; same-wave LDS ops are ordered. Convoys 4 -> 3.
template <bool WS>
__global__ __launch_bounds__(512, 2) void wca_main(
    const float* __restrict__ x1, const float* __restrict__ x2,
    const float* __restrict__ mask,
    const float* __restrict__ qw_f, const float* __restrict__ qb,
    const float* __restrict__ kvw_f, const float* __restrict__ kvb,
    const float* __restrict__ pw_f, const float* __restrict__ pb,
    const float* __restrict__ table,
    const bf16_t* __restrict__ wsb,
    float* __restrict__ out) {
  extern __shared__ char smem[];
  char* RA = smem;
  char* RK = smem + 49152;
  char* RV = smem + 98304;

  const int t = threadIdx.x;
  const int w = t >> 6, l = t & 63, lo = l & 15, hi = l >> 4;
  const int win0 = 2 * blockIdx.x;

  const bf16_t* q_wb = wsb;
  const bf16_t* kv_wb = wsb + 36864;
  const bf16_t* p_wb = wsb + 110592;

  // ---------- stage x2 (both windows) -> RA ----------
  {
    const float4* s2a = (const float4*)(x2 + (size_t)win0 * 12288);
    const float4* s2b = (const float4*)(x2 + (size_t)(win0 + 1) * 12288);
    float4 ld[12];
#pragma unroll
    for (int it = 0; it < 3; ++it) {
      int idx = it * 512 + t;
      ld[4 * it + 0] = s2a[2 * idx]; ld[4 * it + 1] = s2a[2 * idx + 1];
      ld[4 * it + 2] = s2b[2 * idx]; ld[4 * it + 3] = s2b[2 * idx + 1];
    }
#pragma unroll
    for (int it = 0; it < 3; ++it) {
      int idx = it * 512 + t;
      int n = idx / 24, g = idx - n * 24;
      bf16x8 v;
      float4 a = ld[4 * it + 0], c = ld[4 * it + 1];
      v[0] = (bf16_t)a.x; v[1] = (bf16_t)a.y; v[2] = (bf16_t)a.z; v[3] = (bf16_t)a.w;
      v[4] = (bf16_t)c.x; v[5] = (bf16_t)c.y; v[6] = (bf16_t)c.z; v[7] = (bf16_t)c.w;
      *(bf16x8*)(RA + swz(n, g * 16, 384)) = v;
      a = ld[4 * it + 2]; c = ld[4 * it + 3];
      v[0] = (bf16_t)a.x; v[1] = (bf16_t)a.y; v[2] = (bf16_t)a.z; v[3] = (bf16_t)a.w;
      v[4] = (bf16_t)c.x; v[5] = (bf16_t)c.y; v[6] = (bf16_t)c.z; v[7] = (bf16_t)c.w;
      *(bf16x8*)(RA + swz(64 + n, g * 16, 384)) = v;
    }
  }
  barrier_nd();

  // ---------- phase A: KV proj, weights preloaded once, 2 windows ----------
  // wave w: K cols w*48.. (w<4) | V cols (w-4)*48.. (w>=4). Full dedup.
  {
    bf16x8 wA[6][3];
#pragma unroll
    for (int kk = 0; kk < 6; ++kk)
#pragma unroll
      for (int ct = 0; ct < 3; ++ct) {
        int row = w * 48 + ct * 16 + lo;
        wA[kk][ct] = ldw<WS>(kv_wb, kvw_f, row * 192 + kk * 32 + hi * 8);
      }
    for (int wv = 0; wv < 2; ++wv) {
      f32x4 acc[4][3];
#pragma unroll
      for (int rt = 0; rt < 4; ++rt)
#pragma unroll
        for (int ct = 0; ct < 3; ++ct) { f32x4 z = {0.f, 0.f, 0.f, 0.f}; acc[rt][ct] = z; }
#pragma unroll
      for (int kk = 0; kk < 6; ++kk) {
        bf16x8 a[4];
#pragma unroll
        for (int rt = 0; rt < 4; ++rt)
          a[rt] = *(const bf16x8*)(RA + swz(wv * 64 + rt * 16 + lo, (kk * 4 + hi) * 16, 384));
#pragma unroll
        for (int rt = 0; rt < 4; ++rt)
#pragma unroll
          for (int ct = 0; ct < 3; ++ct)
            acc[rt][ct] = mfma16(a[rt], wA[kk][ct], acc[rt][ct]);
      }
      if (w < 4) {
#pragma unroll
        for (int ct = 0; ct < 3; ++ct) {
          int och = w * 48 + ct * 16 + lo;
          float bv = kvb[och];
#pragma unroll
          for (int rt = 0; rt < 4; ++rt)
#pragma unroll
            for (int i = 0; i < 4; ++i)
              *(bf16_t*)(RK + swz(wv * 64 + rt * 16 + hi * 4 + i, och * 2, 384)) =
                  (bf16_t)(acc[rt][ct][i] + bv);
        }
      } else {
#pragma unroll
        for (int ct = 0; ct < 3; ++ct) {
          int och = (w - 4) * 48 + ct * 16 + lo;
          float bv = kvb[192 + och];
#pragma unroll
          for (int rt = 0; rt < 4; ++rt) {
            int n0 = rt * 16 + hi * 4;
            bf16x4 pk;
#pragma unroll
            for (int i = 0; i < 4; ++i) pk[i] = (bf16_t)(acc[rt][ct][i] + bv);
            *(bf16x4*)(RV + wv * 24576 + swz(och, n0 * 2, 128)) = pk;
          }
        }
      }
    }
  }
  barrier_nd();  // x2 reads done; K, V^T ready

  // ---------- phase B: Q proj from global x1 -> RA ----------
  // wave: wv = w>>2, rt2 = (w>>1)&1 (32 rows), cg = w&1 (96 cols)
  {
    const int wv = w >> 2, rt2 = (w >> 1) & 1, cg = w & 1;
    const float* x1w = x1 + (size_t)(win0 + wv) * 12288;
    f32x4 acc[2][6];
#pragma unroll
    for (int rt = 0; rt < 2; ++rt)
#pragma unroll
      for (int ct = 0; ct < 6; ++ct) { f32x4 z = {0.f, 0.f, 0.f, 0.f}; acc[rt][ct] = z; }
#pragma unroll
    for (int kh = 0; kh < 2; ++kh) {
      float4 xf[2][3][2];
#pragma unroll
      for (int rt = 0; rt < 2; ++rt) {
        const float4* p = (const float4*)(x1w + (rt2 * 32 + rt * 16 + lo) * 192);
#pragma unroll
        for (int k2 = 0; k2 < 3; ++k2) {
          xf[rt][k2][0] = p[(kh * 3 + k2) * 8 + hi * 2];
          xf[rt][k2][1] = p[(kh * 3 + k2) * 8 + hi * 2 + 1];
        }
      }
      bf16x8 wB[3][6];
#pragma unroll
      for (int k2 = 0; k2 < 3; ++k2)
#pragma unroll
        for (int ct = 0; ct < 6; ++ct) {
          int col = cg * 96 + ct * 16 + lo;
          wB[k2][ct] = ldw<WS>(q_wb, qw_f, col * 192 + (kh * 3 + k2) * 32 + hi * 8);
        }
#pragma unroll
      for (int k2 = 0; k2 < 3; ++k2)
#pragma unroll
        for (int rt = 0; rt < 2; ++rt) {
          bf16x8 a;
          float4 xa = xf[rt][k2][0], xb = xf[rt][k2][1];
          a[0] = (bf16_t)xa.x; a[1] = (bf16_t)xa.y; a[2] = (bf16_t)xa.z; a[3] = (bf16_t)xa.w;
          a[4] = (bf16_t)xb.x; a[5] = (bf16_t)xb.y; a[6] = (bf16_t)xb.z; a[7] = (bf16_t)xb.w;
#pragma unroll
          for (int ct = 0; ct < 6; ++ct) acc[rt][ct] = mfma16(a, wB[k2][ct], acc[rt][ct]);
        }
    }
#pragma unroll
    for (int ct = 0; ct < 6; ++ct) {
      int col = cg * 96 + ct * 16 + lo;
      float qbs = qb[col] * SCALE;
#pragma unroll
      for (int rt = 0; rt < 2; ++rt)
#pragma unroll
        for (int i = 0; i < 4; ++i) {
          int row = wv * 64 + rt2 * 32 + rt * 16 + hi * 4 + i;
          float val = WS ? (acc[rt][ct][i] + qbs) : (acc[rt][ct][i] + qb[col]) * SCALE;
          *(bf16_t*)(RA + swz(row, col * 2, 384)) = (bf16_t)val;
        }
    }
  }
  // NO barrier here (r15): this wave's attention consumes exactly the Q tile
  // it just wrote (identical wave decode); K/V synced at the A-barrier;
  // same-wave LDS ops are ordered by hardware lgkmcnt.

  // ---------- attention: wave = (wv = w>>2, rt32 = (w>>1)&1, hh = w&1) ----------
  // Per wave: 32 q-rows (2 sub-tiles of 16) x 3 heads. Bias via 5.4 KB table
  // gather (L1-resident). att-out overwrites Q in RA, no barriers.
  {
    const int wv = w >> 2, rt32 = (w >> 1) & 1, hh = w & 1;
    const int win = win0 + wv;
    const float* maskb = mask + (size_t)(win & 1023) * 4096;
    f32x4 mk[2][4];
    int ridx[2][4][4];
#pragma unroll
    for (int rts = 0; rts < 2; ++rts) {
      int r = rt32 * 32 + rts * 16 + lo;
#pragma unroll
      for (int ct = 0; ct < 4; ++ct) {
        mk[rts][ct] = *(const f32x4*)(maskb + r * 64 + ct * 16 + hi * 4);
#pragma unroll
        for (int i = 0; i < 4; ++i) {
          int c = ct * 16 + hi * 4 + i;
          ridx[rts][ct][i] = (((r >> 3) - (c >> 3) + 7) * 15 + ((r & 7) - (c & 7) + 7)) * 6;
        }
      }
    }
#pragma unroll
    for (int hq = 0; hq < 3; ++hq) {
      const int h = hh * 3 + hq;
#pragma unroll
      for (int rts = 0; rts < 2; ++rts) {
        const int rbase = rt32 * 32 + rts * 16;
        const int r = rbase + lo;
        bf16x8 qa = *(const bf16x8*)(RA + swz(wv * 64 + r, h * 64 + hi * 16, 384));
        f32x4 s[4];
#pragma unroll
        for (int ct = 0; ct < 4; ++ct) {
          f32x4 ci;
#pragma unroll
          for (int i = 0; i < 4; ++i) ci[i] = table[ridx[rts][ct][i] + h];
          ci += mk[rts][ct];
          bf16x8 ka = *(const bf16x8*)(RK + swz(wv * 64 + ct * 16 + lo, h * 64 + hi * 16, 384));
          s[ct] = mfma16(ka, qa, ci);  // S^T: lane holds S[r][ct*16+hi*4+i]
        }
        float mx = -1e30f;
#pragma unroll
        for (int ct = 0; ct < 4; ++ct)
#pragma unroll
          for (int i = 0; i < 4; ++i) mx = fmaxf(mx, s[ct][i]);
        mx = fmaxf(mx, __shfl_xor(mx, 16));
        mx = fmaxf(mx, __shfl_xor(mx, 32));
        float sum = 0.f;
#pragma unroll
        for (int ct = 0; ct < 4; ++ct)
#pragma unroll
          for (int i = 0; i < 4; ++i) {
            float p = __expf(s[ct][i] - mx);
            s[ct][i] = p;
            sum += p;
          }
        sum += __shfl_xor(sum, 16);
        sum += __shfl_xor(sum, 32);
        float rinv = 1.0f / sum;
        unsigned int word[4][2];
#pragma unroll
        for (int ct = 0; ct < 4; ++ct)
#pragma unroll
          for (int i2 = 0; i2 < 2; ++i2) {
            CvtU cu;
            cu.h[0] = (bf16_t)(s[ct][2 * i2] * rinv);
            cu.h[1] = (bf16_t)(s[ct][2 * i2 + 1] * rinv);
            word[ct][i2] = cu.u;
          }
        // PV: build A-frag P[rbase+lo][k-run] via shfl word-pulls
        f32x4 o0 = {0.f, 0.f, 0.f, 0.f}, o1 = {0.f, 0.f, 0.f, 0.f};
#pragma unroll
        for (int k2 = 0; k2 < 2; ++k2) {
          PaU pa;
#pragma unroll
          for (int j2 = 0; j2 < 4; ++j2) {
            int src = lo + ((hi & 1) << 5) + ((j2 >> 1) << 4);
            unsigned int wa = (unsigned int)__shfl((int)word[2 * k2][j2 & 1], src);
            unsigned int wb = (unsigned int)__shfl((int)word[2 * k2 + 1][j2 & 1], src);
            pa.u[j2] = (hi & 2) ? wb : wa;
          }
          bf16x8 v0 = *(const bf16x8*)(RV + wv * 24576 + swz(h * 32 + lo, k2 * 64 + hi * 16, 128));
          bf16x8 v1 = *(const bf16x8*)(RV + wv * 24576 + swz(h * 32 + 16 + lo, k2 * 64 + hi * 16, 128));
          o0 = mfma16(pa.v, v0, o0);
          o1 = mfma16(pa.v, v1, o1);
        }
#pragma unroll
        for (int i = 0; i < 4; ++i) {
          int rr = wv * 64 + rbase + hi * 4 + i;
          *(bf16_t*)(RA + swz(rr, h * 64 + lo * 2, 384)) = (bf16_t)o0[i];
          *(bf16_t*)(RA + swz(rr, h * 64 + 32 + lo * 2, 384)) = (bf16_t)o1[i];
        }
      }
    }
  }
  barrier_nd();  // att-out fully in RA

  // ---------- out proj: wave = (wv = w>>2, cgo = w&3 -> 48 cols) ----------
  {
    const int wv = w >> 2, cgo = w & 3;
    bf16x8 wO[6][3];
#pragma unroll
    for (int kk = 0; kk < 6; ++kk)
#pragma unroll
      for (int ct = 0; ct < 3; ++ct) {
        int col = cgo * 48 + ct * 16 + lo;
        wO[kk][ct] = ldw<WS>(p_wb, pw_f, col * 192 + kk * 32 + hi * 8);
      }
    f32x4 acc[4][3];
#pragma unroll
    for (int rt = 0; rt < 4; ++rt)
#pragma unroll
      for (int ct = 0; ct < 3; ++ct) { f32x4 z = {0.f, 0.f, 0.f, 0.f}; acc[rt][ct] = z; }
#pragma unroll
    for (int kk = 0; kk < 6; ++kk) {
      bf16x8 a[4];
#pragma unroll
      for (int rt = 0; rt < 4; ++rt)
        a[rt] = *(const bf16x8*)(RA + swz(wv * 64 + rt * 16 + lo, (kk * 4 + hi) * 16, 384));
#pragma unroll
      for (int rt = 0; rt < 4; ++rt)
#pragma unroll
        for (int ct = 0; ct < 3; ++ct)
          acc[rt][ct] = mfma16(a[rt], wO[kk][ct], acc[rt][ct]);
    }
    float* outp = out + (size_t)(win0 + wv) * 12288;
#pragma unroll
    for (int ct = 0; ct < 3; ++ct) {
      int col = cgo * 48 + ct * 16 + lo;
      float bv = pb[col];
#pragma unroll
      for (int rt = 0; rt < 4; ++rt)
#pragma unroll
        for (int i = 0; i < 4; ++i)
          outp[(rt * 16 + hi * 4 + i) * 192 + col] = acc[rt][ct][i] + bv;
    }
  }
}

extern "C" void kernel_launch(void* const* d_in, const int* in_sizes, int n_in,
                              void* d_out, int out_size, void* d_ws, size_t ws_size,
                              hipStream_t stream) {
  const float* x1 = (const float*)d_in[0];
  const float* x2 = (const float*)d_in[1];
  const float* mask = (const float*)d_in[2];
  const float* qw = (const float*)d_in[3];
  const float* qb = (const float*)d_in[4];
  const float* kvw = (const float*)d_in[5];
  const float* kvb = (const float*)d_in[6];
  const float* pw = (const float*)d_in[7];
  const float* pb = (const float*)d_in[8];
  const float* table = (const float*)d_in[9];
  float* out = (float*)d_out;
  bf16_t* wsb = (bf16_t*)d_ws;
  const int LDS_BYTES = 147456;
  if (ws_size >= 294912) {
    prep<<<144, 256, 0, stream>>>(qw, kvw, pw, wsb);
    wca_main<true><<<4096, 512, LDS_BYTES, stream>>>(x1, x2, mask, qw, qb, kvw, kvb,
                                                     pw, pb, table, wsb, out);
  } else {
    wca_main<false><<<4096, 512, LDS_BYTES, stream>>>(x1, x2, mask, qw, qb, kvw, kvb,
                                                      pw, pb, table, wsb, out);
  }
}